// Round 13
// baseline (541.565 us; speedup 1.0000x reference)
//
#include <hip/hip_runtime.h>
#include <hip/hip_fp16.h>

// Problem constants
#define NB   64     // batch
#define NDEC 12     // decoder steps
#define NF   32     // input features
#define NH   512    // hidden
#define NE   96     // encoder length
#define NT   4      // output dim
#define KI0  (NF + NH)   // 544 = K of layer-0 input GEMM
#define KOUT (2*NH + NF) // 1056 = K of out-proj GEMM

typedef _Float16 half8_t __attribute__((ext_vector_type(8)));
typedef float   float4_t __attribute__((ext_vector_type(4)));

__device__ __forceinline__ float fast_tanh(float x) {
    x = fminf(fmaxf(x, -15.f), 15.f);
    float e = __expf(2.f * x);
    return (e - 1.f) / (e + 1.f);
}
__device__ __forceinline__ float fast_sig(float x) {
    return 1.f / (1.f + __expf(-x));
}

// ---------------------------------------------------------------------------
// One-time: fp32->fp16 weight converts + state init.
__global__ __launch_bounds__(256) void k_prep(
    const float* __restrict__ Wi0, const float* __restrict__ Wh0,
    const float* __restrict__ Wi1, const float* __restrict__ Wh1,
    const float* __restrict__ Wout, const float* __restrict__ Wattn,
    const float* __restrict__ hidden, const float* __restrict__ inputs,
    __half* __restrict__ Wi0h, __half* __restrict__ Wh0h,
    __half* __restrict__ Wi1h, __half* __restrict__ Wh1h,
    __half* __restrict__ Wouth, __half* __restrict__ WahT,
    __half* __restrict__ WaeH,
    float* __restrict__ h0row, float* __restrict__ h1row,
    __half* __restrict__ h0h, __half* __restrict__ h1h,
    __half* __restrict__ xcat0)
{
    int i = blockIdx.x*256 + threadIdx.x;
    const int n0 = 1536*KI0, n1 = 1536*512, n4 = 4*KOUT, n5 = 512*512;
    if (i < n0) { Wi0h[i] = __float2half_rn(Wi0[i]); return; }  i -= n0;
    if (i < n1) { Wh0h[i] = __float2half_rn(Wh0[i]); return; }  i -= n1;
    if (i < n1) { Wi1h[i] = __float2half_rn(Wi1[i]); return; }  i -= n1;
    if (i < n1) { Wh1h[i] = __float2half_rn(Wh1[i]); return; }  i -= n1;
    if (i < n4) { Wouth[i] = __float2half_rn(Wout[i]); return; } i -= n4;
    if (i < n5) {                                     // WahT[k][g] = Wattn[g][k]
        int k = i >> 9, g = i & 511;
        WahT[i] = __float2half_rn(Wattn[(size_t)g*1024 + k]);
        return;
    }
    i -= n5;
    if (i < n5) {                                     // WaeH[g][k] = Wattn[g][512+k]
        int g = i >> 9, k = i & 511;
        WaeH[i] = __float2half_rn(Wattn[(size_t)g*1024 + 512 + k]);
        return;
    }
    i -= n5;
    if (i < NB*NH) {                                  // state init (row-major)
        int b = i >> 9, k = i & 511;
        float v0 = hidden[b*NH + k];
        float v1 = hidden[NB*NH + b*NH + k];
        h0row[b*NH + k] = v0;  h0h[b*NH + k] = __float2half_rn(v0);
        h1row[b*NH + k] = v1;  h1h[b*NH + k] = __float2half_rn(v1);
        return;
    }
    i -= NB*NH;
    if (i < NB*NF) {                                  // cur(0) -> xcat parity 0
        int b = i >> 5, k = i & 31;
        xcat0[(size_t)b*KI0 + k] = __float2half_rn(inputs[b*NDEC*NF + k]);
    }
}

// ---------------------------------------------------------------------------
// enc_proj via MFMA f16: encp[be][g] = sum_k enc[be][k] * WaeH[g][k].
__global__ __launch_bounds__(256) void k_encproj(const float* __restrict__ enc,
                                                 const __half* __restrict__ WaeH,
                                                 __half* __restrict__ encph) {
    int x = blockIdx.x;                 // 768 = 96 (m-tiles) x 8 (n-tiles)
    int by = x >> 3, bx = x & 7;
    int t = threadIdx.x, w = t >> 6, lane = t & 63;
    int mr = lane & 15, kq = lane >> 4;          // kq in 0..3
    int m = by*64 + w*16 + mr;
    const float* arow = enc + (size_t)m*NH;
    float4_t acc[4] = {{0.f,0.f,0.f,0.f},{0.f,0.f,0.f,0.f},
                       {0.f,0.f,0.f,0.f},{0.f,0.f,0.f,0.f}};
    for (int kb = 0; kb < NH; kb += 32) {
        int k = kb + kq*8;
        float4 a0 = *(const float4*)(arow + k);
        float4 a1 = *(const float4*)(arow + k + 4);
        half8_t a;
        a[0] = (_Float16)a0.x; a[1] = (_Float16)a0.y;
        a[2] = (_Float16)a0.z; a[3] = (_Float16)a0.w;
        a[4] = (_Float16)a1.x; a[5] = (_Float16)a1.y;
        a[6] = (_Float16)a1.z; a[7] = (_Float16)a1.w;
        #pragma unroll
        for (int j = 0; j < 4; ++j) {
            int n = bx*64 + j*16 + mr;
            half8_t b = *(const half8_t*)(WaeH + (size_t)n*NH + k);
            acc[j] = __builtin_amdgcn_mfma_f32_16x16x32_f16(a, b, acc[j], 0, 0, 0);
        }
    }
    #pragma unroll
    for (int j = 0; j < 4; ++j) {
        int col = bx*64 + j*16 + mr;
        #pragma unroll
        for (int r = 0; r < 4; ++r) {
            int row = by*64 + w*16 + kq*4 + r;
            encph[(size_t)row*NH + col] = __float2half_rn(acc[j][r]);
        }
    }
}

// ---------------------------------------------------------------------------
// Fused stage 1 (the only per-step serial GEMM+softmax stage):
//  blocks 0..63  : att GEMV (per-b, WahT L2-resident) + scores + softmax + ws
//  blocks 64..255: ghb GEMMs (wide, off critical path)
//  block 256     : out-proj(s-1) + cur(s) scatter
// grid = 257 x 1024.
__global__ __launch_bounds__(1024) void k_soft(
    const float* __restrict__ inputs, const int* __restrict__ tgt,
    const __half* __restrict__ WahT,   // [512 k][512 g]
    const float* __restrict__ battn, const float* __restrict__ vattn,
    const float* __restrict__ h1row,   // [64][512] fp32 h1(s)
    const __half* __restrict__ encph, const float* __restrict__ enc,
    const __half* __restrict__ Wouth, const float* __restrict__ bout,
    const __half* __restrict__ Wh0h, const __half* __restrict__ Wh1h,
    const __half* __restrict__ h0h, const __half* __restrict__ h1h,
    float* __restrict__ ghb,           // [2][3*512][64]
    const __half* __restrict__ xcatP,  // [64][544] parity s-1 (cur/ws old)
    __half* __restrict__ xcatC,        // [64][544] parity s   (cur/ws new)
    float* __restrict__ out, int s)
{
    int blk = blockIdx.x, t = threadIdx.x;
    int lane = t & 63, widx = t >> 6;
    __shared__ float h1s[NH], vs[NH], atts[NH];
    __shared__ float2 attp2[4][256];
    __shared__ float pes[NE], combA[NH], combB[NH];
    __shared__ float invD_sh;
    __shared__ float parts[4][4][16][17];    // ghb path

    if (blk >= 64 && blk < 256) {
        // ---------------- ghb GEMMs (192 wide blocks) ----------------
        int gblk = blk - 64;
        int rt = (gblk & 7)*24 + (gblk >> 3);    // swizzled rowtile 0..191
        int layer = (rt >= 96) ? 1 : 0;
        int rloc = (rt - layer*96) * 16;
        int bq = widx >> 2, wq = widx & 3;
        int mr = lane & 15, kq = lane >> 4;
        const __half* Wh = layer ? Wh1h : Wh0h;
        const __half* Xh = layer ? h1h : h0h;
        const __half* arow = Wh + (size_t)(rloc + mr)*NH;
        const __half* brow = Xh + (size_t)(bq*16 + mr)*NH;
        int kb0 = wq*128 + kq*8;
        half8_t a0 = *(const half8_t*)(arow + kb0);
        half8_t b0 = *(const half8_t*)(brow + kb0);
        half8_t a1 = *(const half8_t*)(arow + kb0 + 32);
        half8_t b1 = *(const half8_t*)(brow + kb0 + 32);
        half8_t a2 = *(const half8_t*)(arow + kb0 + 64);
        half8_t b2 = *(const half8_t*)(brow + kb0 + 64);
        half8_t a3 = *(const half8_t*)(arow + kb0 + 96);
        half8_t b3 = *(const half8_t*)(brow + kb0 + 96);
        float4_t acc = {0.f,0.f,0.f,0.f};
        acc = __builtin_amdgcn_mfma_f32_16x16x32_f16(a0, b0, acc, 0, 0, 0);
        acc = __builtin_amdgcn_mfma_f32_16x16x32_f16(a1, b1, acc, 0, 0, 0);
        acc = __builtin_amdgcn_mfma_f32_16x16x32_f16(a2, b2, acc, 0, 0, 0);
        acc = __builtin_amdgcn_mfma_f32_16x16x32_f16(a3, b3, acc, 0, 0, 0);
        #pragma unroll
        for (int r = 0; r < 4; ++r) parts[bq][wq][kq*4 + r][mr] = acc[r];
        __syncthreads();
        int sub = t >> 8, tt = t & 255;
        int jl = tt >> 4, bl = tt & 15;
        float v = parts[sub][0][jl][bl] + parts[sub][1][jl][bl]
                + parts[sub][2][jl][bl] + parts[sub][3][jl][bl];
        ghb[((size_t)layer*3*NH + rloc + jl)*NB + sub*16 + bl] = v;
        return;
    }

    if (blk == 256) {
        // -------- out-proj(s-1) + cur(s) scatter (4 waves) --------
        if (s == 0 || widx >= 4) return;
        int mr = lane & 15, kq = lane >> 4;
        int b = widx*16 + mr;
        const __half* h1b = h1h + (size_t)b*NH;
        const __half* xcb = xcatP + (size_t)b*KI0;   // [cur(s-1) | ws(s-1)]
        int ar = (mr < 4) ? mr : 3;
        const __half* arow = Wouth + (size_t)ar*KOUT;
        float4_t acc = {0.f,0.f,0.f,0.f};
        for (int kb = 0; kb < KOUT; kb += 32) {
            int k = kb + kq*8;
            half8_t a = *(const half8_t*)(arow + k);
            const __half* bp = (k < NH)   ? (h1b + k)
                             : (k < 2*NH) ? (xcb + NF + (k - NH))
                                          : (xcb + (k - 2*NH));
            half8_t bb = *(const half8_t*)bp;
            acc = __builtin_amdgcn_mfma_f32_16x16x32_f16(a, bb, acc, 0, 0, 0);
        }
        float o0 = __shfl(acc[0], mr) + bout[0];
        float o1 = __shfl(acc[1], mr) + bout[1];
        float o2 = __shfl(acc[2], mr) + bout[2];
        float o3 = __shfl(acc[3], mr) + bout[3];
        if (kq == 0) {
            *(float4*)(out + (size_t)b*(NDEC*NT) + (s-1)*NT) = make_float4(o0,o1,o2,o3);
        }
        int t0 = tgt[0], t1 = tgt[1], t2 = tgt[2], t3 = tgt[3];
        const float* ip = inputs + (size_t)b*(NDEC*NF) + (s-1)*NF;
        half8_t hv;
        #pragma unroll
        for (int i = 0; i < 8; ++i) {
            int f = kq*8 + i;
            float v = ip[f];
            v = (f == t0) ? o0 : (f == t1) ? o1 : (f == t2) ? o2 : (f == t3) ? o3 : v;
            hv[i] = (_Float16)__float2half_rn(v);
        }
        *(half8_t*)(xcatC + (size_t)b*KI0 + kq*8) = hv;
        return;
    }

    // ---------------- att GEMV + softmax/ws path (blocks 0..63) ----------------
    int b = blk;
    if (t < NH) { h1s[t] = h1row[(size_t)b*NH + t]; vs[t] = vattn[t]; }

    // prefetch ws-phase enc values (48 per thread); issued before att GEMV
    float er[48];
    {
        int k = t & 511, half = t >> 9;
        const float* eb = enc + ((size_t)b*NE + half*48)*NH + k;
        #pragma unroll
        for (int e = 0; e < 48; ++e) er[e] = eb[(size_t)e*NH];
    }
    __syncthreads();

    // att[g] = h1 . Wa_h[g] + battn[g]; coalesced: lane covers g-pairs
    {
        int g2 = t & 255, kqa = t >> 8;   // 4 K-quarters of 128
        float a0 = 0.f, a1 = 0.f;
        #pragma unroll 4
        for (int k = kqa*128; k < kqa*128 + 128; ++k) {
            float2 f = __half22float2(*(const __half2*)(WahT + (size_t)k*NH + g2*2));
            float h = h1s[k];
            a0 += f.x*h; a1 += f.y*h;
        }
        attp2[kqa][g2] = make_float2(a0, a1);
    }
    __syncthreads();
    if (t < NH) {
        int g = t;
        float2 p0 = attp2[0][g>>1], p1 = attp2[1][g>>1];
        float2 p2 = attp2[2][g>>1], p3 = attp2[3][g>>1];
        float v = (g & 1) ? (p0.y + p1.y + p2.y + p3.y)
                          : (p0.x + p1.x + p2.x + p3.x);
        atts[g] = v + battn[g];
    }
    __syncthreads();

    // scores -> exp (no max-subtract: |score| small)
    {
        float ar[8], vr[8];
        #pragma unroll
        for (int i = 0; i < 8; ++i) { ar[i] = atts[lane*8 + i]; vr[i] = vs[lane*8 + i]; }
        for (int it = 0; it < 6; ++it) {
            int e = widx + it*16;
            const __half* ep = encph + ((size_t)(b*NE + e))*NH + lane*8;
            uint4 u = *(const uint4*)ep;
            __half2 p0 = *(__half2*)&u.x, p1 = *(__half2*)&u.y;
            __half2 p2 = *(__half2*)&u.z, p3 = *(__half2*)&u.w;
            float2 f0 = __half22float2(p0), f1 = __half22float2(p1);
            float2 f2 = __half22float2(p2), f3 = __half22float2(p3);
            float sacc;
            sacc  = fast_tanh(f0.x + ar[0]) * vr[0];
            sacc += fast_tanh(f0.y + ar[1]) * vr[1];
            sacc += fast_tanh(f1.x + ar[2]) * vr[2];
            sacc += fast_tanh(f1.y + ar[3]) * vr[3];
            sacc += fast_tanh(f2.x + ar[4]) * vr[4];
            sacc += fast_tanh(f2.y + ar[5]) * vr[5];
            sacc += fast_tanh(f3.x + ar[6]) * vr[6];
            sacc += fast_tanh(f3.y + ar[7]) * vr[7];
            #pragma unroll
            for (int off = 32; off; off >>= 1) sacc += __shfl_down(sacc, off);
            if (lane == 0) pes[e] = __expf(sacc);
        }
    }
    __syncthreads();

    if (t < 64) {
        float v = pes[t] + ((t < 32) ? pes[64 + t] : 0.f);
        #pragma unroll
        for (int off = 32; off; off >>= 1) v += __shfl_down(v, off);
        if (t == 0) invD_sh = 1.f / v;
    }
    __syncthreads();

    // ws[k] = sum_e p[e] * enc[b,e,k]  (enc values already in registers)
    {
        int k = t & 511, half = t >> 9;
        float acc = 0.f;
        #pragma unroll
        for (int e = 0; e < 48; ++e) acc += pes[half*48 + e] * er[e];
        if (half == 0) combA[k] = acc; else combB[k] = acc;
    }
    __syncthreads();
    if (t < NH) {
        float v = (combA[t] + combB[t]) * invD_sh;
        xcatC[(size_t)b*KI0 + NF + t] = __float2half_rn(v);
    }
}

// ---------------------------------------------------------------------------
// GRU input-half via MFMA (K-split x4) + gate combine.
// grid = 128 blocks x 768 threads (12 waves = 3 gates x 4 K-chunks).
// XCD swizzle: sblk = (blk%8)*16 + blk/8.
__global__ __launch_bounds__(768) void k_gru(
    const __half* __restrict__ Wi,
    const float* __restrict__ bi, const float* __restrict__ bh,
    const __half* __restrict__ xh, int K,     // [64][K] fp16
    const float* __restrict__ ghbL,           // [3*512][64] Wh . hold
    const float* __restrict__ hold,           // [64][512] fp32
    float* __restrict__ hnew,                 // [64][512] fp32 (may == hold)
    __half* __restrict__ hnewh)               // [64][512] fp16
{
    int blk = blockIdx.x, t = threadIdx.x;
    int w = t >> 6, lane = t & 63;
    int mr = lane & 15, kq = lane >> 4;
    int sblk = (blk & 7)*16 + (blk >> 3);     // XCD swizzle (bijective)
    int jg = sblk >> 2, bq = sblk & 3;
    int j0 = jg*16, b0 = bq*16;
    __shared__ float parts[3][4][16][17];     // [gate][kchunk][j][b]

    // ---- prefetch combine-phase operands (threads 0..255) ----
    float ghr = 0.f, ghz = 0.f, ghn = 0.f, hp = 0.f;
    float biR = 0.f, bhR = 0.f, biZ = 0.f, bhZ = 0.f, biN = 0.f, bhN = 0.f;
    if (t < 256) {
        int jl = t >> 4, bl = t & 15;
        int j = j0 + jl, b = b0 + bl;
        ghr = ghbL[(size_t)(0*NH + j)*NB + b];
        ghz = ghbL[(size_t)(1*NH + j)*NB + b];
        ghn = ghbL[(size_t)(2*NH + j)*NB + b];
        hp  = hold[(size_t)b*NH + j];
        biR = bi[j];        bhR = bh[j];
        biZ = bi[NH + j];   bhZ = bh[NH + j];
        biN = bi[2*NH + j]; bhN = bh[2*NH + j];
    }

    int gate = w >> 2, c = w & 3;
    int nsteps = K >> 5;                      // 17 (K=544) or 16 (K=512)
    int rem = nsteps & 3;
    int base = c*(nsteps >> 2) + ((c < rem) ? c : rem);
    int cnt  = (nsteps >> 2) + ((c < rem) ? 1 : 0);
    const __half* arow = Wi + (size_t)(gate*NH + j0 + mr)*K;
    const __half* brow = xh + (size_t)(b0 + mr)*K;
    float4_t acc = {0.f,0.f,0.f,0.f};
    for (int i2 = 0; i2 < cnt; ++i2) {
        int kb = (base + i2)*32;
        half8_t a = *(const half8_t*)(arow + kb + kq*8);
        half8_t b = *(const half8_t*)(brow + kb + kq*8);
        acc = __builtin_amdgcn_mfma_f32_16x16x32_f16(a, b, acc, 0, 0, 0);
    }
    #pragma unroll
    for (int r = 0; r < 4; ++r) parts[gate][c][kq*4 + r][mr] = acc[r];
    __syncthreads();

    if (t < 256) {
        int jl = t >> 4, bl = t & 15;
        int j = j0 + jl, b = b0 + bl;
        float S0 = parts[0][0][jl][bl] + parts[0][1][jl][bl]
                 + parts[0][2][jl][bl] + parts[0][3][jl][bl];
        float S1 = parts[1][0][jl][bl] + parts[1][1][jl][bl]
                 + parts[1][2][jl][bl] + parts[1][3][jl][bl];
        float S2 = parts[2][0][jl][bl] + parts[2][1][jl][bl]
                 + parts[2][2][jl][bl] + parts[2][3][jl][bl];
        float r = fast_sig(S0 + ghr + biR + bhR);
        float z = fast_sig(S1 + ghz + biZ + bhZ);
        float n = fast_tanh(S2 + biN + r*(ghn + bhN));
        float hv = (1.f - z)*n + z*hp;
        hnew[(size_t)b*NH + j] = hv;
        hnewh[(size_t)b*NH + j] = __float2half_rn(hv);
    }
}

// ---------------------------------------------------------------------------
// Final out(NDEC-1) projection (1 block x 256).
__global__ __launch_bounds__(256) void k_outp(
    const __half* __restrict__ Wouth, const float* __restrict__ bout,
    const __half* __restrict__ h1h, const __half* __restrict__ xcatP,
    float* __restrict__ out)
{
    int t = threadIdx.x;
    int w = t >> 6, lane = t & 63;
    int mr = lane & 15, kq = lane >> 4;
    int b = w*16 + mr;
    const __half* h1b = h1h + (size_t)b*NH;
    const __half* xcb = xcatP + (size_t)b*KI0;
    int ar = (mr < 4) ? mr : 3;
    const __half* arow = Wouth + (size_t)ar*KOUT;
    float4_t acc = {0.f,0.f,0.f,0.f};
    for (int kb = 0; kb < KOUT; kb += 32) {
        int k = kb + kq*8;
        half8_t a = *(const half8_t*)(arow + k);
        const __half* bp = (k < NH)   ? (h1b + k)
                         : (k < 2*NH) ? (xcb + NF + (k - NH))
                                      : (xcb + (k - 2*NH));
        half8_t bb = *(const half8_t*)bp;
        acc = __builtin_amdgcn_mfma_f32_16x16x32_f16(a, bb, acc, 0, 0, 0);
    }
    float o0 = __shfl(acc[0], mr) + bout[0];
    float o1 = __shfl(acc[1], mr) + bout[1];
    float o2 = __shfl(acc[2], mr) + bout[2];
    float o3 = __shfl(acc[3], mr) + bout[3];
    if (kq == 0) {
        *(float4*)(out + (size_t)b*(NDEC*NT) + (NDEC-1)*NT) = make_float4(o0,o1,o2,o3);
    }
}

// ---------------------------------------------------------------------------
extern "C" void kernel_launch(void* const* d_in, const int* in_sizes, int n_in,
                              void* d_out, int out_size, void* d_ws, size_t ws_size,
                              hipStream_t stream) {
    const float* inputs = (const float*)d_in[0];
    const float* hidden = (const float*)d_in[1];
    const float* enc    = (const float*)d_in[2];
    const int*   tgt    = (const int*)d_in[3];
    const float* Wattn  = (const float*)d_in[4];
    const float* battn  = (const float*)d_in[5];
    const float* vattn  = (const float*)d_in[6];
    const float* Wi0    = (const float*)d_in[7];
    const float* Wh0    = (const float*)d_in[8];
    const float* bi0    = (const float*)d_in[9];
    const float* bh0    = (const float*)d_in[10];
    const float* Wi1    = (const float*)d_in[11];
    const float* Wh1    = (const float*)d_in[12];
    const float* bi1    = (const float*)d_in[13];
    const float* bh1    = (const float*)d_in[14];
    const float* Wout   = (const float*)d_in[15];
    const float* bout   = (const float*)d_in[16];
    float* out = (float*)d_out;

    // Workspace (~15.1 MiB)
    float* h0row  = (float*)d_ws;             // [64][512]
    float* h1row  = h0row + NB*NH;            // [64][512]
    float* ghb    = h1row + NB*NH;            // [2][3*512][64]
    __half* Wi0h  = (__half*)(ghb + 2*3*NH*NB);  // 1536 x 544
    __half* Wh0h  = Wi0h + 1536*KI0;          // 1536 x 512
    __half* Wi1h  = Wh0h + 1536*NH;           // 1536 x 512
    __half* Wh1h  = Wi1h + 1536*NH;           // 1536 x 512
    __half* Wouth = Wh1h + 1536*NH;           // 4 x 1056
    __half* WahT  = Wouth + 4*KOUT;           // [512 k][512 g]
    __half* WaeH  = WahT + NH*NH;             // [512 g][512 k]
    __half* h0h   = WaeH + NH*NH;             // [64][512]
    __half* h1h   = h0h + NB*NH;              // [64][512]
    __half* xcat  = h1h + NB*NH;              // 2 x [64][544] (parity)
    __half* encph = xcat + 2*NB*KI0;          // [6144][512]

    const int prep_n = 1536*KI0 + 3*1536*NH + 4*KOUT + 2*NH*NH + NB*NH + NB*NF;
    k_prep<<<(prep_n + 255)/256, 256, 0, stream>>>(
        Wi0, Wh0, Wi1, Wh1, Wout, Wattn, hidden, inputs,
        Wi0h, Wh0h, Wi1h, Wh1h, Wouth, WahT, WaeH,
        h0row, h1row, h0h, h1h, xcat);
    k_encproj<<<768, 256, 0, stream>>>(enc, WaeH, encph);

    for (int s = 0; s < NDEC; ++s) {
        int par = s & 1;
        __half* xcatC = xcat + par*NB*KI0;
        __half* xcatP = xcat + (par^1)*NB*KI0;
        k_soft<<<257, 1024, 0, stream>>>(
            inputs, tgt, WahT, battn, vattn, h1row, encph, enc,
            Wouth, bout, Wh0h, Wh1h, h0h, h1h, ghb, xcatP, xcatC, out, s);
        k_gru<<<128, 768, 0, stream>>>(Wi0h, bi0, bh0,
                                       xcatC, KI0,
                                       ghb,
                                       h0row, h0row, h0h);
        k_gru<<<128, 768, 0, stream>>>(Wi1h, bi1, bh1,
                                       h0h, NH,
                                       ghb + 3*NH*NB,
                                       h1row, h1row, h1h);
    }
    // Final: out(11) from h1(12), ws(11), cur(11) (parity 11&1 = 1)
    k_outp<<<1, 256, 0, stream>>>(Wouth, bout, h1h, xcat + (NB*KI0), out);
}

// Round 14
// 483.297 us; speedup vs baseline: 1.1206x; 1.1206x over previous
//
#include <hip/hip_runtime.h>
#include <hip/hip_fp16.h>

// Problem constants
#define NB   64     // batch
#define NDEC 12     // decoder steps
#define NF   32     // input features
#define NH   512    // hidden
#define NE   96     // encoder length
#define NT   4      // output dim
#define KI0  (NF + NH)   // 544 = K of layer-0 input GEMM
#define KOUT (2*NH + NF) // 1056 = K of out-proj GEMM

typedef _Float16 half8_t __attribute__((ext_vector_type(8)));
typedef float   float4_t __attribute__((ext_vector_type(4)));

__device__ __forceinline__ float fast_tanh(float x) {
    x = fminf(fmaxf(x, -15.f), 15.f);
    float e = __expf(2.f * x);
    return (e - 1.f) / (e + 1.f);
}
__device__ __forceinline__ float fast_sig(float x) {
    return 1.f / (1.f + __expf(-x));
}

// ---------------------------------------------------------------------------
// One-time: fp32->fp16 weight converts + state init.
__global__ __launch_bounds__(256) void k_prep(
    const float* __restrict__ Wi0, const float* __restrict__ Wh0,
    const float* __restrict__ Wi1, const float* __restrict__ Wh1,
    const float* __restrict__ Wout, const float* __restrict__ Wattn,
    const float* __restrict__ hidden, const float* __restrict__ inputs,
    __half* __restrict__ Wi0h, __half* __restrict__ Wh0h,
    __half* __restrict__ Wi1h, __half* __restrict__ Wh1h,
    __half* __restrict__ Wouth, __half* __restrict__ WahH,
    __half* __restrict__ WaeH,
    float* __restrict__ h0row, float* __restrict__ h1row,
    __half* __restrict__ h0h, __half* __restrict__ h1h,
    __half* __restrict__ xcat0)
{
    int i = blockIdx.x*256 + threadIdx.x;
    const int n0 = 1536*KI0, n1 = 1536*512, n4 = 4*KOUT, n5 = 512*512;
    if (i < n0) { Wi0h[i] = __float2half_rn(Wi0[i]); return; }  i -= n0;
    if (i < n1) { Wh0h[i] = __float2half_rn(Wh0[i]); return; }  i -= n1;
    if (i < n1) { Wi1h[i] = __float2half_rn(Wi1[i]); return; }  i -= n1;
    if (i < n1) { Wh1h[i] = __float2half_rn(Wh1[i]); return; }  i -= n1;
    if (i < n4) { Wouth[i] = __float2half_rn(Wout[i]); return; } i -= n4;
    if (i < n5) {                                     // WahH[g][k] = Wattn[g][k]
        int g = i >> 9, k = i & 511;
        WahH[i] = __float2half_rn(Wattn[(size_t)g*1024 + k]);
        return;
    }
    i -= n5;
    if (i < n5) {                                     // WaeH[g][k] = Wattn[g][512+k]
        int g = i >> 9, k = i & 511;
        WaeH[i] = __float2half_rn(Wattn[(size_t)g*1024 + 512 + k]);
        return;
    }
    i -= n5;
    if (i < NB*NH) {                                  // state init (row-major)
        int b = i >> 9, k = i & 511;
        float v0 = hidden[b*NH + k];
        float v1 = hidden[NB*NH + b*NH + k];
        h0row[b*NH + k] = v0;  h0h[b*NH + k] = __float2half_rn(v0);
        h1row[b*NH + k] = v1;  h1h[b*NH + k] = __float2half_rn(v1);
        return;
    }
    i -= NB*NH;
    if (i < NB*NF) {                                  // cur(0) -> xcat parity 0
        int b = i >> 5, k = i & 31;
        xcat0[(size_t)b*KI0 + k] = __float2half_rn(inputs[b*NDEC*NF + k]);
    }
}

// ---------------------------------------------------------------------------
// enc_proj via MFMA f16: encp[be][g] = sum_k enc[be][k] * WaeH[g][k].
__global__ __launch_bounds__(256) void k_encproj(const float* __restrict__ enc,
                                                 const __half* __restrict__ WaeH,
                                                 __half* __restrict__ encph) {
    int x = blockIdx.x;                 // 768 = 96 (m-tiles) x 8 (n-tiles)
    int by = x >> 3, bx = x & 7;
    int t = threadIdx.x, w = t >> 6, lane = t & 63;
    int mr = lane & 15, kq = lane >> 4;          // kq in 0..3
    int m = by*64 + w*16 + mr;
    const float* arow = enc + (size_t)m*NH;
    float4_t acc[4] = {{0.f,0.f,0.f,0.f},{0.f,0.f,0.f,0.f},
                       {0.f,0.f,0.f,0.f},{0.f,0.f,0.f,0.f}};
    for (int kb = 0; kb < NH; kb += 32) {
        int k = kb + kq*8;
        float4 a0 = *(const float4*)(arow + k);
        float4 a1 = *(const float4*)(arow + k + 4);
        half8_t a;
        a[0] = (_Float16)a0.x; a[1] = (_Float16)a0.y;
        a[2] = (_Float16)a0.z; a[3] = (_Float16)a0.w;
        a[4] = (_Float16)a1.x; a[5] = (_Float16)a1.y;
        a[6] = (_Float16)a1.z; a[7] = (_Float16)a1.w;
        #pragma unroll
        for (int j = 0; j < 4; ++j) {
            int n = bx*64 + j*16 + mr;
            half8_t b = *(const half8_t*)(WaeH + (size_t)n*NH + k);
            acc[j] = __builtin_amdgcn_mfma_f32_16x16x32_f16(a, b, acc[j], 0, 0, 0);
        }
    }
    #pragma unroll
    for (int j = 0; j < 4; ++j) {
        int col = bx*64 + j*16 + mr;
        #pragma unroll
        for (int r = 0; r < 4; ++r) {
            int row = by*64 + w*16 + kq*4 + r;
            encph[(size_t)row*NH + col] = __float2half_rn(acc[j][r]);
        }
    }
}

// ---------------------------------------------------------------------------
// att GEMM only: attT[b][g] = (Wa_h @ h1^T)[g][b] + battn[g].
// grid = 32 blocks x 1024 (16 waves): block = one 16-row weight panel x all
// 64 batches. Wave (bq = w>>2, wq = w&3) = K-quarter of tile (rt, bq).
// XCD swizzle 32 = 8x4.
__global__ __launch_bounds__(1024) void k_att(
    const __half* __restrict__ WahH, const float* __restrict__ battn,
    const __half* __restrict__ h1h,
    float* __restrict__ attcT)         // [64 b][512 g]
{
    int blk = blockIdx.x, t = threadIdx.x;
    int w = t >> 6, lane = t & 63;
    int mr = lane & 15, kq = lane >> 4;
    int rt = (blk & 7)*4 + (blk >> 3);           // swizzled rowtile 0..31
    int rt16 = rt*16;
    int bq = w >> 2, wq = w & 3;
    __shared__ float parts[4][4][16][17];        // [bq][wq][j][b]

    float bat = battn[rt16 + (t & 15)];          // prefetch epilogue operand
    const __half* arow = WahH + (size_t)(rt16 + mr)*NH;
    const __half* brow = h1h + (size_t)(bq*16 + mr)*NH;
    int kb0 = wq*128 + kq*8;
    half8_t a0 = *(const half8_t*)(arow + kb0);
    half8_t b0 = *(const half8_t*)(brow + kb0);
    half8_t a1 = *(const half8_t*)(arow + kb0 + 32);
    half8_t b1 = *(const half8_t*)(brow + kb0 + 32);
    half8_t a2 = *(const half8_t*)(arow + kb0 + 64);
    half8_t b2 = *(const half8_t*)(brow + kb0 + 64);
    half8_t a3 = *(const half8_t*)(arow + kb0 + 96);
    half8_t b3 = *(const half8_t*)(brow + kb0 + 96);
    float4_t acc = {0.f,0.f,0.f,0.f};
    acc = __builtin_amdgcn_mfma_f32_16x16x32_f16(a0, b0, acc, 0, 0, 0);
    acc = __builtin_amdgcn_mfma_f32_16x16x32_f16(a1, b1, acc, 0, 0, 0);
    acc = __builtin_amdgcn_mfma_f32_16x16x32_f16(a2, b2, acc, 0, 0, 0);
    acc = __builtin_amdgcn_mfma_f32_16x16x32_f16(a3, b3, acc, 0, 0, 0);
    #pragma unroll
    for (int r = 0; r < 4; ++r) parts[bq][wq][kq*4 + r][mr] = acc[r];
    __syncthreads();

    int sub = t >> 8, tt = t & 255;              // sub == bq thread range
    int jl = tt & 15, bl = tt >> 4;              // T-write: g fast -> coalesced
    float v = parts[sub][0][jl][bl] + parts[sub][1][jl][bl]
            + parts[sub][2][jl][bl] + parts[sub][3][jl][bl];
    attcT[(size_t)(sub*16 + bl)*NH + rt16 + jl] = v + bat;
}

// ---------------------------------------------------------------------------
// Fused stage 2: softmax/ws (blocks 0..63) || ghb GEMMs (64..255) ||
// out-proj(s-1)+cur(s) (block 256). grid = 257 x 1024.
__global__ __launch_bounds__(1024) void k_soft(
    const float* __restrict__ inputs, const int* __restrict__ tgt,
    const float* __restrict__ vattn,
    const float* __restrict__ attcT,   // [64 b][512 g], battn included
    const __half* __restrict__ encph, const float* __restrict__ enc,
    const __half* __restrict__ Wouth, const float* __restrict__ bout,
    const __half* __restrict__ Wh0h, const __half* __restrict__ Wh1h,
    const __half* __restrict__ h0h, const __half* __restrict__ h1h,
    float* __restrict__ ghb,           // [2][3*512][64]
    const __half* __restrict__ xcatP,  // [64][544] parity s-1 (cur/ws old)
    __half* __restrict__ xcatC,        // [64][544] parity s   (cur/ws new)
    float* __restrict__ out, int s)
{
    int blk = blockIdx.x, t = threadIdx.x;
    int lane = t & 63, widx = t >> 6;
    __shared__ float vs[NH], atts[NH];
    __shared__ float pes[NE], combA[NH], combB[NH];
    __shared__ float invD_sh;
    __shared__ float parts[4][4][16][17];    // ghb path

    if (blk >= 64 && blk < 256) {
        // ---------------- ghb GEMMs (192 wide blocks) ----------------
        int gblk = blk - 64;
        int rt = (gblk & 7)*24 + (gblk >> 3);    // swizzled rowtile 0..191
        int layer = (rt >= 96) ? 1 : 0;
        int rloc = (rt - layer*96) * 16;
        int bq = widx >> 2, wq = widx & 3;
        int mr = lane & 15, kq = lane >> 4;
        const __half* Wh = layer ? Wh1h : Wh0h;
        const __half* Xh = layer ? h1h : h0h;
        const __half* arow = Wh + (size_t)(rloc + mr)*NH;
        const __half* brow = Xh + (size_t)(bq*16 + mr)*NH;
        int kb0 = wq*128 + kq*8;
        half8_t a0 = *(const half8_t*)(arow + kb0);
        half8_t b0 = *(const half8_t*)(brow + kb0);
        half8_t a1 = *(const half8_t*)(arow + kb0 + 32);
        half8_t b1 = *(const half8_t*)(brow + kb0 + 32);
        half8_t a2 = *(const half8_t*)(arow + kb0 + 64);
        half8_t b2 = *(const half8_t*)(brow + kb0 + 64);
        half8_t a3 = *(const half8_t*)(arow + kb0 + 96);
        half8_t b3 = *(const half8_t*)(brow + kb0 + 96);
        float4_t acc = {0.f,0.f,0.f,0.f};
        acc = __builtin_amdgcn_mfma_f32_16x16x32_f16(a0, b0, acc, 0, 0, 0);
        acc = __builtin_amdgcn_mfma_f32_16x16x32_f16(a1, b1, acc, 0, 0, 0);
        acc = __builtin_amdgcn_mfma_f32_16x16x32_f16(a2, b2, acc, 0, 0, 0);
        acc = __builtin_amdgcn_mfma_f32_16x16x32_f16(a3, b3, acc, 0, 0, 0);
        #pragma unroll
        for (int r = 0; r < 4; ++r) parts[bq][wq][kq*4 + r][mr] = acc[r];
        __syncthreads();
        int sub = t >> 8, tt = t & 255;
        int jl = tt >> 4, bl = tt & 15;
        float v = parts[sub][0][jl][bl] + parts[sub][1][jl][bl]
                + parts[sub][2][jl][bl] + parts[sub][3][jl][bl];
        ghb[((size_t)layer*3*NH + rloc + jl)*NB + sub*16 + bl] = v;
        return;
    }

    if (blk == 256) {
        // -------- out-proj(s-1) + cur(s) scatter (4 waves) --------
        if (s == 0 || widx >= 4) return;
        int mr = lane & 15, kq = lane >> 4;
        int b = widx*16 + mr;
        const __half* h1b = h1h + (size_t)b*NH;
        const __half* xcb = xcatP + (size_t)b*KI0;   // [cur(s-1) | ws(s-1)]
        int ar = (mr < 4) ? mr : 3;
        const __half* arow = Wouth + (size_t)ar*KOUT;
        float4_t acc = {0.f,0.f,0.f,0.f};
        for (int kb = 0; kb < KOUT; kb += 32) {
            int k = kb + kq*8;
            half8_t a = *(const half8_t*)(arow + k);
            const __half* bp = (k < NH)   ? (h1b + k)
                             : (k < 2*NH) ? (xcb + NF + (k - NH))
                                          : (xcb + (k - 2*NH));
            half8_t bb = *(const half8_t*)bp;
            acc = __builtin_amdgcn_mfma_f32_16x16x32_f16(a, bb, acc, 0, 0, 0);
        }
        float o0 = __shfl(acc[0], mr) + bout[0];
        float o1 = __shfl(acc[1], mr) + bout[1];
        float o2 = __shfl(acc[2], mr) + bout[2];
        float o3 = __shfl(acc[3], mr) + bout[3];
        if (kq == 0) {
            *(float4*)(out + (size_t)b*(NDEC*NT) + (s-1)*NT) = make_float4(o0,o1,o2,o3);
        }
        int t0 = tgt[0], t1 = tgt[1], t2 = tgt[2], t3 = tgt[3];
        const float* ip = inputs + (size_t)b*(NDEC*NF) + (s-1)*NF;
        half8_t hv;
        #pragma unroll
        for (int i = 0; i < 8; ++i) {
            int f = kq*8 + i;
            float v = ip[f];
            v = (f == t0) ? o0 : (f == t1) ? o1 : (f == t2) ? o2 : (f == t3) ? o3 : v;
            hv[i] = (_Float16)__float2half_rn(v);
        }
        *(half8_t*)(xcatC + (size_t)b*KI0 + kq*8) = hv;
        return;
    }

    // ---------------- softmax/ws path (blocks 0..63) ----------------
    int b = blk;
    if (t < NH) { vs[t] = vattn[t]; atts[t] = attcT[(size_t)b*NH + t]; }

    // prefetch ws-phase enc values (48 per thread)
    float er[48];
    {
        int k = t & 511, half = t >> 9;
        const float* eb = enc + ((size_t)b*NE + half*48)*NH + k;
        #pragma unroll
        for (int e = 0; e < 48; ++e) er[e] = eb[(size_t)e*NH];
    }
    __syncthreads();

    // scores -> exp (no max-subtract: |score| small)
    {
        float ar[8], vr[8];
        #pragma unroll
        for (int i = 0; i < 8; ++i) { ar[i] = atts[lane*8 + i]; vr[i] = vs[lane*8 + i]; }
        for (int it = 0; it < 6; ++it) {
            int e = widx + it*16;
            const __half* ep = encph + ((size_t)(b*NE + e))*NH + lane*8;
            uint4 u = *(const uint4*)ep;
            __half2 p0 = *(__half2*)&u.x, p1 = *(__half2*)&u.y;
            __half2 p2 = *(__half2*)&u.z, p3 = *(__half2*)&u.w;
            float2 f0 = __half22float2(p0), f1 = __half22float2(p1);
            float2 f2 = __half22float2(p2), f3 = __half22float2(p3);
            float sacc;
            sacc  = fast_tanh(f0.x + ar[0]) * vr[0];
            sacc += fast_tanh(f0.y + ar[1]) * vr[1];
            sacc += fast_tanh(f1.x + ar[2]) * vr[2];
            sacc += fast_tanh(f1.y + ar[3]) * vr[3];
            sacc += fast_tanh(f2.x + ar[4]) * vr[4];
            sacc += fast_tanh(f2.y + ar[5]) * vr[5];
            sacc += fast_tanh(f3.x + ar[6]) * vr[6];
            sacc += fast_tanh(f3.y + ar[7]) * vr[7];
            #pragma unroll
            for (int off = 32; off; off >>= 1) sacc += __shfl_down(sacc, off);
            if (lane == 0) pes[e] = __expf(sacc);
        }
    }
    __syncthreads();

    if (t < 64) {
        float v = pes[t] + ((t < 32) ? pes[64 + t] : 0.f);
        #pragma unroll
        for (int off = 32; off; off >>= 1) v += __shfl_down(v, off);
        if (t == 0) invD_sh = 1.f / v;
    }
    __syncthreads();

    // ws[k] = sum_e p[e] * enc[b,e,k]  (enc values already in registers)
    {
        int k = t & 511, half = t >> 9;
        float acc = 0.f;
        #pragma unroll
        for (int e = 0; e < 48; ++e) acc += pes[half*48 + e] * er[e];
        if (half == 0) combA[k] = acc; else combB[k] = acc;
    }
    __syncthreads();
    if (t < NH) {
        float v = (combA[t] + combB[t]) * invD_sh;
        xcatC[(size_t)b*KI0 + NF + t] = __float2half_rn(v);
    }
}

// ---------------------------------------------------------------------------
// GRU input-half via MFMA (K-split x4) + gate combine.
// grid = 128 blocks x 768 threads (12 waves = 3 gates x 4 K-chunks).
// XCD swizzle: sblk = (blk%8)*16 + blk/8.
__global__ __launch_bounds__(768) void k_gru(
    const __half* __restrict__ Wi,
    const float* __restrict__ bi, const float* __restrict__ bh,
    const __half* __restrict__ xh, int K,     // [64][K] fp16
    const float* __restrict__ ghbL,           // [3*512][64] Wh . hold
    const float* __restrict__ hold,           // [64][512] fp32
    float* __restrict__ hnew,                 // [64][512] fp32 (may == hold)
    __half* __restrict__ hnewh)               // [64][512] fp16
{
    int blk = blockIdx.x, t = threadIdx.x;
    int w = t >> 6, lane = t & 63;
    int mr = lane & 15, kq = lane >> 4;
    int sblk = (blk & 7)*16 + (blk >> 3);     // XCD swizzle (bijective)
    int jg = sblk >> 2, bq = sblk & 3;
    int j0 = jg*16, b0 = bq*16;
    __shared__ float parts[3][4][16][17];     // [gate][kchunk][j][b]

    // ---- prefetch combine-phase operands (threads 0..255) ----
    float ghr = 0.f, ghz = 0.f, ghn = 0.f, hp = 0.f;
    float biR = 0.f, bhR = 0.f, biZ = 0.f, bhZ = 0.f, biN = 0.f, bhN = 0.f;
    if (t < 256) {
        int jl = t >> 4, bl = t & 15;
        int j = j0 + jl, b = b0 + bl;
        ghr = ghbL[(size_t)(0*NH + j)*NB + b];
        ghz = ghbL[(size_t)(1*NH + j)*NB + b];
        ghn = ghbL[(size_t)(2*NH + j)*NB + b];
        hp  = hold[(size_t)b*NH + j];
        biR = bi[j];        bhR = bh[j];
        biZ = bi[NH + j];   bhZ = bh[NH + j];
        biN = bi[2*NH + j]; bhN = bh[2*NH + j];
    }

    int gate = w >> 2, c = w & 3;
    int nsteps = K >> 5;                      // 17 (K=544) or 16 (K=512)
    int rem = nsteps & 3;
    int base = c*(nsteps >> 2) + ((c < rem) ? c : rem);
    int cnt  = (nsteps >> 2) + ((c < rem) ? 1 : 0);
    const __half* arow = Wi + (size_t)(gate*NH + j0 + mr)*K;
    const __half* brow = xh + (size_t)(b0 + mr)*K;
    float4_t acc = {0.f,0.f,0.f,0.f};
    for (int i2 = 0; i2 < cnt; ++i2) {
        int kb = (base + i2)*32;
        half8_t a = *(const half8_t*)(arow + kb + kq*8);
        half8_t b = *(const half8_t*)(brow + kb + kq*8);
        acc = __builtin_amdgcn_mfma_f32_16x16x32_f16(a, b, acc, 0, 0, 0);
    }
    #pragma unroll
    for (int r = 0; r < 4; ++r) parts[gate][c][kq*4 + r][mr] = acc[r];
    __syncthreads();

    if (t < 256) {
        int jl = t >> 4, bl = t & 15;
        int j = j0 + jl, b = b0 + bl;
        float S0 = parts[0][0][jl][bl] + parts[0][1][jl][bl]
                 + parts[0][2][jl][bl] + parts[0][3][jl][bl];
        float S1 = parts[1][0][jl][bl] + parts[1][1][jl][bl]
                 + parts[1][2][jl][bl] + parts[1][3][jl][bl];
        float S2 = parts[2][0][jl][bl] + parts[2][1][jl][bl]
                 + parts[2][2][jl][bl] + parts[2][3][jl][bl];
        float r = fast_sig(S0 + ghr + biR + bhR);
        float z = fast_sig(S1 + ghz + biZ + bhZ);
        float n = fast_tanh(S2 + biN + r*(ghn + bhN));
        float hv = (1.f - z)*n + z*hp;
        hnew[(size_t)b*NH + j] = hv;
        hnewh[(size_t)b*NH + j] = __float2half_rn(hv);
    }
}

// ---------------------------------------------------------------------------
// Final out(NDEC-1) projection (1 block x 256).
__global__ __launch_bounds__(256) void k_outp(
    const __half* __restrict__ Wouth, const float* __restrict__ bout,
    const __half* __restrict__ h1h, const __half* __restrict__ xcatP,
    float* __restrict__ out)
{
    int t = threadIdx.x;
    int w = t >> 6, lane = t & 63;
    int mr = lane & 15, kq = lane >> 4;
    int b = w*16 + mr;
    const __half* h1b = h1h + (size_t)b*NH;
    const __half* xcb = xcatP + (size_t)b*KI0;
    int ar = (mr < 4) ? mr : 3;
    const __half* arow = Wouth + (size_t)ar*KOUT;
    float4_t acc = {0.f,0.f,0.f,0.f};
    for (int kb = 0; kb < KOUT; kb += 32) {
        int k = kb + kq*8;
        half8_t a = *(const half8_t*)(arow + k);
        const __half* bp = (k < NH)   ? (h1b + k)
                         : (k < 2*NH) ? (xcb + NF + (k - NH))
                                      : (xcb + (k - 2*NH));
        half8_t bb = *(const half8_t*)bp;
        acc = __builtin_amdgcn_mfma_f32_16x16x32_f16(a, bb, acc, 0, 0, 0);
    }
    float o0 = __shfl(acc[0], mr) + bout[0];
    float o1 = __shfl(acc[1], mr) + bout[1];
    float o2 = __shfl(acc[2], mr) + bout[2];
    float o3 = __shfl(acc[3], mr) + bout[3];
    if (kq == 0) {
        *(float4*)(out + (size_t)b*(NDEC*NT) + (NDEC-1)*NT) = make_float4(o0,o1,o2,o3);
    }
}

// ---------------------------------------------------------------------------
extern "C" void kernel_launch(void* const* d_in, const int* in_sizes, int n_in,
                              void* d_out, int out_size, void* d_ws, size_t ws_size,
                              hipStream_t stream) {
    const float* inputs = (const float*)d_in[0];
    const float* hidden = (const float*)d_in[1];
    const float* enc    = (const float*)d_in[2];
    const int*   tgt    = (const int*)d_in[3];
    const float* Wattn  = (const float*)d_in[4];
    const float* battn  = (const float*)d_in[5];
    const float* vattn  = (const float*)d_in[6];
    const float* Wi0    = (const float*)d_in[7];
    const float* Wh0    = (const float*)d_in[8];
    const float* bi0    = (const float*)d_in[9];
    const float* bh0    = (const float*)d_in[10];
    const float* Wi1    = (const float*)d_in[11];
    const float* Wh1    = (const float*)d_in[12];
    const float* bi1    = (const float*)d_in[13];
    const float* bh1    = (const float*)d_in[14];
    const float* Wout   = (const float*)d_in[15];
    const float* bout   = (const float*)d_in[16];
    float* out = (float*)d_out;

    // Workspace (~15.2 MiB)
    float* h0row  = (float*)d_ws;             // [64][512]
    float* h1row  = h0row + NB*NH;            // [64][512]
    float* ghb    = h1row + NB*NH;            // [2][3*512][64]
    float* attcT  = ghb + 2*3*NH*NB;          // [64][512]
    __half* Wi0h  = (__half*)(attcT + NB*NH); // 1536 x 544
    __half* Wh0h  = Wi0h + 1536*KI0;          // 1536 x 512
    __half* Wi1h  = Wh0h + 1536*NH;           // 1536 x 512
    __half* Wh1h  = Wi1h + 1536*NH;           // 1536 x 512
    __half* Wouth = Wh1h + 1536*NH;           // 4 x 1056
    __half* WahH  = Wouth + 4*KOUT;           // [512 g][512 k]
    __half* WaeH  = WahH + NH*NH;             // [512 g][512 k]
    __half* h0h   = WaeH + NH*NH;             // [64][512]
    __half* h1h   = h0h + NB*NH;              // [64][512]
    __half* xcat  = h1h + NB*NH;              // 2 x [64][544] (parity)
    __half* encph = xcat + 2*NB*KI0;          // [6144][512]

    const int prep_n = 1536*KI0 + 3*1536*NH + 4*KOUT + 2*NH*NH + NB*NH + NB*NF;
    k_prep<<<(prep_n + 255)/256, 256, 0, stream>>>(
        Wi0, Wh0, Wi1, Wh1, Wout, Wattn, hidden, inputs,
        Wi0h, Wh0h, Wi1h, Wh1h, Wouth, WahH, WaeH,
        h0row, h1row, h0h, h1h, xcat);
    k_encproj<<<768, 256, 0, stream>>>(enc, WaeH, encph);

    for (int s = 0; s < NDEC; ++s) {
        int par = s & 1;
        __half* xcatC = xcat + par*NB*KI0;
        __half* xcatP = xcat + (par^1)*NB*KI0;
        k_att<<<32, 1024, 0, stream>>>(WahH, battn, h1h, attcT);
        k_soft<<<257, 1024, 0, stream>>>(
            inputs, tgt, vattn, attcT, encph, enc, Wouth, bout,
            Wh0h, Wh1h, h0h, h1h, ghb, xcatP, xcatC, out, s);
        k_gru<<<128, 768, 0, stream>>>(Wi0h, bi0, bh0,
                                       xcatC, KI0,
                                       ghb,
                                       h0row, h0row, h0h);
        k_gru<<<128, 768, 0, stream>>>(Wi1h, bi1, bh1,
                                       h0h, NH,
                                       ghb + 3*NH*NB,
                                       h1row, h1row, h1h);
    }
    // Final: out(11) from h1(12), ws(11), cur(11) (parity 11&1 = 1)
    k_outp<<<1, 256, 0, stream>>>(Wouth, bout, h1h, xcat + (NB*KI0), out);
}